// Round 2
// baseline (301.178 us; speedup 1.0000x reference)
//
#include <hip/hip_runtime.h>
#include <hip/hip_bf16.h>
#include <stdint.h>

typedef __attribute__((ext_vector_type(8))) __bf16 bf16x8;
typedef __attribute__((ext_vector_type(4))) float  f32x4;
typedef __attribute__((ext_vector_type(16))) float f32x16;

__device__ __forceinline__ ushort f2bf(float f) {
    union { float f; uint32_t u; } v; v.f = f;
    uint32_t u = v.u;
    uint32_t r = 0x7FFFu + ((u >> 16) & 1u);
    return (ushort)((u + r) >> 16);
}
__device__ __forceinline__ float bf2f(ushort u) {
    union { uint32_t u; float f; } v; v.u = ((uint32_t)u) << 16;
    return v.f;
}

// async global->LDS, 16B per lane; LDS dest must be wave-uniform base + lane*16
typedef __attribute__((address_space(3))) uint32_t lds_u32_t;
typedef const __attribute__((address_space(1))) uint32_t glb_u32_t;
__device__ __forceinline__ void async_copy16(const void* g, void* l) {
    __builtin_amdgcn_global_load_lds((glb_u32_t*)g, (lds_u32_t*)l, 16, 0, 0);
}

// ---------------- convert fp32 -> bf16 (vectorized) ----------------
__global__ __launch_bounds__(256) void convert_bf16(const float* __restrict__ src,
                                                    ushort* __restrict__ dst, int n4) {
    int i = blockIdx.x * 256 + threadIdx.x;
    if (i < n4) {
        float4 f = ((const float4*)src)[i];
        ushort4 o;
        o.x = f2bf(f.x); o.y = f2bf(f.y); o.z = f2bf(f.z); o.w = f2bf(f.w);
        ((ushort4*)dst)[i] = o;
    }
}

// ---------------- QKV projection GEMM: Y = X @ W^T + b ----------------
// X: [4096,1024] bf16, W: [1024,1024] bf16 (row-major [N,K]).
// z=0 -> k ([B,H,S,DH]), z=1 -> q ([B,H,S,DH]), z=2 -> v transposed ([B,H,DH,S]).
__global__ __launch_bounds__(256) void proj_gemm(
    const ushort* __restrict__ xb, const ushort* __restrict__ wball,
    const float* __restrict__ bk, const float* __restrict__ bq, const float* __restrict__ bv,
    ushort* __restrict__ kd, ushort* __restrict__ qd, ushort* __restrict__ vd)
{
    __shared__ ushort As[128 * 32];
    __shared__ ushort Bs[128 * 32];
    const int z = blockIdx.z;
    const int row0 = blockIdx.x * 128;
    const int col0 = blockIdx.y * 128;
    const ushort* wb = wball + z * 1048576;
    const int tid = threadIdx.x;
    const int lane = tid & 63, wave = tid >> 6;
    const int quad = lane >> 4, m15 = lane & 15;
    const int wr = wave >> 1, wc = wave & 1;

    f32x4 acc[4][4];
    for (int i = 0; i < 4; i++)
        for (int j = 0; j < 4; j++) acc[i][j] = (f32x4){0.f, 0.f, 0.f, 0.f};

    for (int kk = 0; kk < 1024; kk += 32) {
        __syncthreads();
        #pragma unroll
        for (int i = 0; i < 2; i++) {
            int c = tid + i * 256;          // 512 chunks of 16B per tile
            int r = c >> 2, off = (c & 3) * 8;
            // LDS byte offset = c*16 -> lane-contiguous: async OK
            async_copy16(&xb[(row0 + r) * 1024 + kk + off], &As[c * 8]);
            async_copy16(&wb[(col0 + r) * 1024 + kk + off], &Bs[c * 8]);
        }
        __syncthreads();
        bf16x8 af[4], bfv[4];
        #pragma unroll
        for (int fr = 0; fr < 4; fr++)
            af[fr] = *(const bf16x8*)&As[(wr * 64 + fr * 16 + m15) * 32 + quad * 8];
        #pragma unroll
        for (int fc = 0; fc < 4; fc++)
            bfv[fc] = *(const bf16x8*)&Bs[(wc * 64 + fc * 16 + m15) * 32 + quad * 8];
        #pragma unroll
        for (int fr = 0; fr < 4; fr++)
            #pragma unroll
            for (int fc = 0; fc < 4; fc++)
                acc[fr][fc] = __builtin_amdgcn_mfma_f32_16x16x32_bf16(af[fr], bfv[fc], acc[fr][fc], 0, 0, 0);
    }

    const float* bias = (z == 0) ? bk : (z == 1) ? bq : bv;
    ushort* dstA = (z == 0) ? kd : qd;
    for (int fr = 0; fr < 4; fr++) {
        int ibase = row0 + wr * 64 + fr * 16 + quad * 4;
        int b_ = ibase >> 10, s = ibase & 1023;
        for (int fc = 0; fc < 4; fc++) {
            int j = col0 + wc * 64 + fc * 16 + m15;
            int h = j >> 6, dh = j & 63;
            float bb = bias[j];
            if (z < 2) {
                for (int r = 0; r < 4; r++)
                    dstA[((b_ * 16 + h) * 1024 + (s + r)) * 64 + dh] = f2bf(acc[fr][fc][r] + bb);
            } else {
                ushort4 o;
                o.x = f2bf(acc[fr][fc][0] + bb);
                o.y = f2bf(acc[fr][fc][1] + bb);
                o.z = f2bf(acc[fr][fc][2] + bb);
                o.w = f2bf(acc[fr][fc][3] + bb);
                *(ushort4*)&vd[((b_ * 16 + h) * 64 + dh) * 1024 + s] = o;
            }
        }
    }
}

// ---------------- lm[m,s,u] = sum_r mask1[m,r,s]*mask2[m,r,u] ----------------
__global__ __launch_bounds__(256) void mask_lr(const float* __restrict__ m1,
                                               const float* __restrict__ m2,
                                               float* __restrict__ lm)
{
    __shared__ float As[64 * 64];
    __shared__ float Bs2[64 * 64];
    const int m = blockIdx.z;
    const int s0 = blockIdx.x * 64, u0 = blockIdx.y * 64;
    const int tid = threadIdx.x;
    for (int i = 0; i < 4; i++) {
        int c = tid + i * 256;              // 1024 float4 chunks
        int r = c >> 4, off = (c & 15) * 4;
        *(float4*)&As[r * 64 + off]  = *(const float4*)&m1[(m * 64 + r) * 1024 + s0 + off];
        *(float4*)&Bs2[r * 64 + off] = *(const float4*)&m2[(m * 64 + r) * 1024 + u0 + off];
    }
    __syncthreads();
    const int tx = tid & 15, ty = tid >> 4;
    float acc[4][4] = {};
    for (int r = 0; r < 64; r++) {
        float4 a = *(const float4*)&As[r * 64 + ty * 4];
        float4 b = *(const float4*)&Bs2[r * 64 + tx * 4];
        float aa[4] = {a.x, a.y, a.z, a.w}, bb[4] = {b.x, b.y, b.z, b.w};
        for (int i = 0; i < 4; i++)
            for (int j = 0; j < 4; j++) acc[i][j] += aa[i] * bb[j];
    }
    for (int i = 0; i < 4; i++) {
        float4 o = {acc[i][0], acc[i][1], acc[i][2], acc[i][3]};
        *(float4*)&lm[(m * 1024 + s0 + ty * 4 + i) * 1024 + u0 + tx * 4] = o;
    }
}

// -------- gathered[m,s,t] = bf16( lm[m,s,rb[m,s,t]] * 0.125 ) --------
__global__ __launch_bounds__(256) void mask_gather(const float* __restrict__ lm,
                                                   const int* __restrict__ rb,
                                                   ushort* __restrict__ gth)
{
    __shared__ float row[1024];
    const int s = blockIdx.x, m = blockIdx.y;
    const int tid = threadIdx.x;
    const int base = (m * 1024 + s) * 1024;
    *(float4*)&row[tid * 4] = *(const float4*)&lm[base + tid * 4];
    __syncthreads();
    int4 idx = ((const int4*)(rb + base))[tid];
    ushort4 o;
    o.x = f2bf(row[idx.x & 1023] * 0.125f);
    o.y = f2bf(row[idx.y & 1023] * 0.125f);
    o.z = f2bf(row[idx.z & 1023] * 0.125f);
    o.w = f2bf(row[idx.w & 1023] * 0.125f);
    ((ushort4*)(gth + base))[tid] = o;
}

// ---------------- fused attention: O_unnorm = (QK^T*mask) @ V ; ss = sum P^2 ----------------
// q,k: [B,H,S,64] bf16 ; v: [B,H,64,S] bf16 ; gth: [4,S,S] bf16 (scale folded in)
__global__ __launch_bounds__(256) void attention(
    const ushort* __restrict__ qd, const ushort* __restrict__ kd, const ushort* __restrict__ vd,
    const ushort* __restrict__ gth, float* __restrict__ O, float* __restrict__ ss)
{
    __shared__ ushort Ks[64 * 72];
    __shared__ ushort Vs[64 * 72];
    __shared__ ushort Ps[64 * 72];
    __shared__ ushort Ms[64 * 72];   // holds Q during prologue, then mask tiles
    __shared__ float red[4];
    const int s0 = blockIdx.x * 64;
    const int bh = blockIdx.y;
    const int mm = bh & 3;           // h = bh & 15; mm = h & 3 = bh & 3
    const int tid = threadIdx.x, lane = tid & 63, wave = tid >> 6;
    const int l31 = lane & 31, hl = lane >> 5;
    const int wr2 = wave >> 1, wc2 = wave & 1;

    // stage Q tile into Ms, pull A-frags to registers, then Ms is free for mask
    #pragma unroll
    for (int i = 0; i < 2; i++) {
        int c = tid + i * 256;
        int r = c >> 3, off = (c & 7) * 8;
        *(uint4*)&Ms[r * 72 + off] = *(const uint4*)&qd[(bh * 1024 + s0 + r) * 64 + off];
    }
    __syncthreads();
    bf16x8 qf[4];
    #pragma unroll
    for (int kk = 0; kk < 4; kk++)
        qf[kk] = *(const bf16x8*)&Ms[(wr2 * 32 + l31) * 72 + kk * 16 + hl * 8];
    __syncthreads();

    f32x16 oacc;
    #pragma unroll
    for (int i = 0; i < 16; i++) oacc[i] = 0.f;
    float ssacc = 0.f;
    const ushort* gbase = gth + mm * 1048576 + s0 * 1024;

    // register prefetch of first K/V/M tiles
    uint4 kr[2], vr[2], mr[2];
    #pragma unroll
    for (int i = 0; i < 2; i++) {
        int c = tid + i * 256;
        int r = c >> 3, off = (c & 7) * 8;
        kr[i] = *(const uint4*)&kd[(bh * 1024 + r) * 64 + off];
        vr[i] = *(const uint4*)&vd[(bh * 64 + r) * 1024 + off];
        mr[i] = *(const uint4*)&gbase[r * 1024 + off];
    }

    for (int t0 = 0; t0 < 1024; t0 += 64) {
        __syncthreads();                   // prev-iter readers done before restage
        #pragma unroll
        for (int i = 0; i < 2; i++) {
            int c = tid + i * 256;
            int r = c >> 3, off = (c & 7) * 8;
            *(uint4*)&Ks[r * 72 + off] = kr[i];
            *(uint4*)&Vs[r * 72 + off] = vr[i];
            *(uint4*)&Ms[r * 72 + off] = mr[i];
        }
        __syncthreads();
        // prefetch next tile (in flight during compute)
        int tn = (t0 + 64 < 1024) ? t0 + 64 : t0;
        #pragma unroll
        for (int i = 0; i < 2; i++) {
            int c = tid + i * 256;
            int r = c >> 3, off = (c & 7) * 8;
            kr[i] = *(const uint4*)&kd[(bh * 1024 + tn + r) * 64 + off];
            vr[i] = *(const uint4*)&vd[(bh * 64 + r) * 1024 + tn + off];
            mr[i] = *(const uint4*)&gbase[r * 1024 + tn + off];
        }

        // QK^T: wave computes P tile rows [wr2*32,+32), cols [wc2*32,+32)
        f32x16 p;
        #pragma unroll
        for (int i = 0; i < 16; i++) p[i] = 0.f;
        #pragma unroll
        for (int kk = 0; kk < 4; kk++) {
            bf16x8 b = *(const bf16x8*)&Ks[(wc2 * 32 + l31) * 72 + kk * 16 + hl * 8];
            p = __builtin_amdgcn_mfma_f32_32x32x16_bf16(qf[kk], b, p, 0, 0, 0);
        }
        // multiply by mask (from LDS), accumulate square-sum, write P tile
        {
            const int col = wc2 * 32 + l31;
            #pragma unroll
            for (int reg = 0; reg < 16; reg++) {
                int row = wr2 * 32 + (reg & 3) + 8 * (reg >> 2) + 4 * hl;
                float pv = p[reg] * bf2f(Ms[row * 72 + col]);
                ssacc += pv * pv;
                Ps[row * 72 + col] = f2bf(pv);
            }
        }
        __syncthreads();
        // PV: wave computes O rows [wr2*32,+32), dh cols [wc2*32,+32)
        #pragma unroll
        for (int kk = 0; kk < 4; kk++) {
            bf16x8 a = *(const bf16x8*)&Ps[(wr2 * 32 + l31) * 72 + kk * 16 + hl * 8];
            bf16x8 b = *(const bf16x8*)&Vs[(wc2 * 32 + l31) * 72 + kk * 16 + hl * 8];
            oacc = __builtin_amdgcn_mfma_f32_32x32x16_bf16(a, b, oacc, 0, 0, 0);
        }
    }
    #pragma unroll
    for (int reg = 0; reg < 16; reg++) {
        int s = s0 + wr2 * 32 + (reg & 3) + 8 * (reg >> 2) + 4 * hl;
        int dh = wc2 * 32 + l31;
        O[(bh * 1024 + s) * 64 + dh] = oacc[reg];
    }
    for (int off = 32; off; off >>= 1) ssacc += __shfl_down(ssacc, off, 64);
    if (lane == 0) red[wave] = ssacc;
    __syncthreads();
    if (tid == 0) atomicAdd(&ss[bh], red[0] + red[1] + red[2] + red[3]);
}

// ---------------- normalize + transpose to [B,S,H,DH] ----------------
__global__ __launch_bounds__(256) void normalize_out(const float* __restrict__ O,
                                                     const float* __restrict__ ss,
                                                     float* __restrict__ out)
{
    int gid = blockIdx.x * 256 + threadIdx.x;
    int e = gid * 4;
    int bh = e >> 16;
    float inv = 1.f / (sqrtf(ss[bh]) + 1e-8f);
    float4 v4 = *(const float4*)&O[e];
    int b_ = bh >> 4, h = bh & 15;
    int s = (e >> 6) & 1023, dh = e & 63;
    float4 o4 = {v4.x * inv, v4.y * inv, v4.z * inv, v4.w * inv};
    *(float4*)&out[((b_ * 1024 + s) * 16 + h) * 64 + dh] = o4;
}

extern "C" void kernel_launch(void* const* d_in, const int* in_sizes, int n_in,
                              void* d_out, int out_size, void* d_ws, size_t ws_size,
                              hipStream_t stream) {
    const float* x  = (const float*)d_in[0];
    const float* Wk = (const float*)d_in[1];
    const float* bk = (const float*)d_in[2];
    const float* Wq = (const float*)d_in[3];
    const float* bq = (const float*)d_in[4];
    const float* Wv = (const float*)d_in[5];
    const float* bv = (const float*)d_in[6];
    const float* m1 = (const float*)d_in[7];
    const float* m2 = (const float*)d_in[8];
    const int*   rb = (const int*)d_in[9];
    float* out = (float*)d_out;

    char* ws = (char*)d_ws;
    ushort* xb    = (ushort*)(ws);                  //  8 MB  [4096,1024] bf16
    ushort* wball = (ushort*)(ws + 8388608);        //  6 MB  3x[1024,1024] bf16
    ushort* kd    = (ushort*)(ws + 14680064);       //  8 MB  [B,H,S,DH] bf16
    ushort* qd    = (ushort*)(ws + 23068672);       //  8 MB
    ushort* vd    = (ushort*)(ws + 31457280);       //  8 MB  [B,H,DH,S] bf16
    float*  lm    = (float*)(ws + 39845888);        // 16 MB  [M,S,S] f32 (reused as O)
    ushort* gth   = (ushort*)(ws + 56623104);       //  8 MB  [M,S,S] bf16
    float*  ssb   = (float*)(ws + 65011712);        // 64 f32

    convert_bf16<<<4096, 256, 0, stream>>>(x,  xb, 1048576);
    convert_bf16<<<1024, 256, 0, stream>>>(Wk, wball,           262144);
    convert_bf16<<<1024, 256, 0, stream>>>(Wq, wball + 1048576, 262144);
    convert_bf16<<<1024, 256, 0, stream>>>(Wv, wball + 2097152, 262144);
    proj_gemm<<<dim3(32, 8, 3), 256, 0, stream>>>(xb, wball, bk, bq, bv, kd, qd, vd);
    mask_lr<<<dim3(16, 16, 4), 256, 0, stream>>>(m1, m2, lm);
    mask_gather<<<dim3(1024, 4), 256, 0, stream>>>(lm, rb, gth);
    hipMemsetAsync(ssb, 0, 64 * sizeof(float), stream);
    float* O = lm;   // lm dead after mask_gather
    attention<<<dim3(16, 64), 256, 0, stream>>>(qd, kd, vd, gth, O, ssb);
    normalize_out<<<4096, 256, 0, stream>>>(O, ssb, out);
}

// Round 3
// 214.602 us; speedup vs baseline: 1.4034x; 1.4034x over previous
//
#include <hip/hip_runtime.h>
#include <hip/hip_bf16.h>
#include <stdint.h>

typedef __attribute__((ext_vector_type(8))) __bf16 bf16x8;
typedef __attribute__((ext_vector_type(4))) float  f32x4;
typedef __attribute__((ext_vector_type(16))) float f32x16;

__device__ __forceinline__ ushort f2bf(float f) {
    union { float f; uint32_t u; } v; v.f = f;
    uint32_t u = v.u;
    uint32_t r = 0x7FFFu + ((u >> 16) & 1u);
    return (ushort)((u + r) >> 16);
}
__device__ __forceinline__ float bf2f(ushort u) {
    union { uint32_t u; float f; } v; v.u = ((uint32_t)u) << 16;
    return v.f;
}

// async global->LDS, 16B per lane; LDS dest must be wave-uniform base + lane*16
typedef __attribute__((address_space(3))) uint32_t lds_u32_t;
typedef const __attribute__((address_space(1))) uint32_t glb_u32_t;
__device__ __forceinline__ void async_copy16(const void* g, void* l) {
    __builtin_amdgcn_global_load_lds((glb_u32_t*)g, (lds_u32_t*)l, 16, 0, 0);
}

// ------------- merged convert fp32 -> bf16: x then Wk,Wq,Wv -------------
__global__ __launch_bounds__(256) void convert_all(
    const float* __restrict__ x, const float* __restrict__ wk,
    const float* __restrict__ wq, const float* __restrict__ wv,
    ushort* __restrict__ xb, ushort* __restrict__ wball)
{
    int i = blockIdx.x * 256 + threadIdx.x;   // 1835008 float4 chunks total
    const float* src; ushort* dst; int j;
    if (i < 1048576) { src = x; dst = xb; j = i; }
    else {
        int t = i - 1048576;
        int z = t >> 18;             // 0..2
        j = t & 262143;
        src = (z == 0) ? wk : (z == 1) ? wq : wv;
        dst = wball + z * 1048576;
    }
    float4 f = ((const float4*)src)[j];
    ushort4 o;
    o.x = f2bf(f.x); o.y = f2bf(f.y); o.z = f2bf(f.z); o.w = f2bf(f.w);
    ((ushort4*)dst)[j] = o;
}

// ---------------- QKV projection GEMM: Y = X @ W^T + b ----------------
// X: [4096,1024] bf16, W: [1024,1024] bf16 (row-major [N,K]).
// z=0 -> k ([B,H,S,DH]), z=1 -> q ([B,H,S,DH]), z=2 -> v transposed ([B,H,DH,S]).
__global__ __launch_bounds__(256) void proj_gemm(
    const ushort* __restrict__ xb, const ushort* __restrict__ wball,
    const float* __restrict__ bk, const float* __restrict__ bq, const float* __restrict__ bv,
    ushort* __restrict__ kd, ushort* __restrict__ qd, ushort* __restrict__ vd)
{
    __shared__ ushort As[128 * 32];
    __shared__ ushort Bs[128 * 32];
    const int z = blockIdx.z;
    const int row0 = blockIdx.x * 128;
    const int col0 = blockIdx.y * 128;
    const ushort* wb = wball + z * 1048576;
    const int tid = threadIdx.x;
    const int lane = tid & 63, wave = tid >> 6;
    const int quad = lane >> 4, m15 = lane & 15;
    const int wr = wave >> 1, wc = wave & 1;

    f32x4 acc[4][4];
    for (int i = 0; i < 4; i++)
        for (int j = 0; j < 4; j++) acc[i][j] = (f32x4){0.f, 0.f, 0.f, 0.f};

    for (int kk = 0; kk < 1024; kk += 32) {
        __syncthreads();
        #pragma unroll
        for (int i = 0; i < 2; i++) {
            int c = tid + i * 256;          // 512 chunks of 16B per tile
            int r = c >> 2, off = (c & 3) * 8;
            async_copy16(&xb[(row0 + r) * 1024 + kk + off], &As[c * 8]);
            async_copy16(&wb[(col0 + r) * 1024 + kk + off], &Bs[c * 8]);
        }
        __syncthreads();
        bf16x8 af[4], bfv[4];
        #pragma unroll
        for (int fr = 0; fr < 4; fr++)
            af[fr] = *(const bf16x8*)&As[(wr * 64 + fr * 16 + m15) * 32 + quad * 8];
        #pragma unroll
        for (int fc = 0; fc < 4; fc++)
            bfv[fc] = *(const bf16x8*)&Bs[(wc * 64 + fc * 16 + m15) * 32 + quad * 8];
        #pragma unroll
        for (int fr = 0; fr < 4; fr++)
            #pragma unroll
            for (int fc = 0; fc < 4; fc++)
                acc[fr][fc] = __builtin_amdgcn_mfma_f32_16x16x32_bf16(af[fr], bfv[fc], acc[fr][fc], 0, 0, 0);
    }

    const float* bias = (z == 0) ? bk : (z == 1) ? bq : bv;
    ushort* dstA = (z == 0) ? kd : qd;
    for (int fr = 0; fr < 4; fr++) {
        int ibase = row0 + wr * 64 + fr * 16 + quad * 4;
        int b_ = ibase >> 10, s = ibase & 1023;
        for (int fc = 0; fc < 4; fc++) {
            int j = col0 + wc * 64 + fc * 16 + m15;
            int h = j >> 6, dh = j & 63;
            float bb = bias[j];
            if (z < 2) {
                for (int r = 0; r < 4; r++)
                    dstA[((b_ * 16 + h) * 1024 + (s + r)) * 64 + dh] = f2bf(acc[fr][fc][r] + bb);
            } else {
                ushort4 o;
                o.x = f2bf(acc[fr][fc][0] + bb);
                o.y = f2bf(acc[fr][fc][1] + bb);
                o.z = f2bf(acc[fr][fc][2] + bb);
                o.w = f2bf(acc[fr][fc][3] + bb);
                *(ushort4*)&vd[((b_ * 16 + h) * 64 + dh) * 1024 + s] = o;
            }
        }
    }
}

// ---------------- lm[m,s,u] = sum_r mask1[m,r,s]*mask2[m,r,u] ----------------
__global__ __launch_bounds__(256) void mask_lr(const float* __restrict__ m1,
                                               const float* __restrict__ m2,
                                               float* __restrict__ lm)
{
    __shared__ float As[64 * 64];
    __shared__ float Bs2[64 * 64];
    const int m = blockIdx.z;
    const int s0 = blockIdx.x * 64, u0 = blockIdx.y * 64;
    const int tid = threadIdx.x;
    for (int i = 0; i < 4; i++) {
        int c = tid + i * 256;              // 1024 float4 chunks
        int r = c >> 4, off = (c & 15) * 4;
        *(float4*)&As[r * 64 + off]  = *(const float4*)&m1[(m * 64 + r) * 1024 + s0 + off];
        *(float4*)&Bs2[r * 64 + off] = *(const float4*)&m2[(m * 64 + r) * 1024 + u0 + off];
    }
    __syncthreads();
    const int tx = tid & 15, ty = tid >> 4;
    float acc[4][4] = {};
    for (int r = 0; r < 64; r++) {
        float4 a = *(const float4*)&As[r * 64 + ty * 4];
        float4 b = *(const float4*)&Bs2[r * 64 + tx * 4];
        float aa[4] = {a.x, a.y, a.z, a.w}, bb[4] = {b.x, b.y, b.z, b.w};
        for (int i = 0; i < 4; i++)
            for (int j = 0; j < 4; j++) acc[i][j] += aa[i] * bb[j];
    }
    for (int i = 0; i < 4; i++) {
        float4 o = {acc[i][0], acc[i][1], acc[i][2], acc[i][3]};
        *(float4*)&lm[(m * 1024 + s0 + ty * 4 + i) * 1024 + u0 + tx * 4] = o;
    }
}

// -------- gathered[m,s,t] = bf16( lm[m,s,rb[m,s,t]] * 0.125 ) --------
__global__ __launch_bounds__(256) void mask_gather(const float* __restrict__ lm,
                                                   const int* __restrict__ rb,
                                                   ushort* __restrict__ gth)
{
    __shared__ float row[1024];
    const int s = blockIdx.x, m = blockIdx.y;
    const int tid = threadIdx.x;
    const int base = (m * 1024 + s) * 1024;
    *(float4*)&row[tid * 4] = *(const float4*)&lm[base + tid * 4];
    __syncthreads();
    int4 idx = ((const int4*)(rb + base))[tid];
    ushort4 o;
    o.x = f2bf(row[idx.x & 1023] * 0.125f);
    o.y = f2bf(row[idx.y & 1023] * 0.125f);
    o.z = f2bf(row[idx.z & 1023] * 0.125f);
    o.w = f2bf(row[idx.w & 1023] * 0.125f);
    ((ushort4*)(gth + base))[tid] = o;
}

// ---------------- fused attention: O_unnorm = (QK^T*mask) @ V ; ss = sum P^2 ----------------
// q,k: [B,H,S,64] bf16 ; v: [B,H,64,S] bf16 ; gth: [4,S,S] bf16 (scale folded in)
__global__ __launch_bounds__(256, 2) void attention(
    const ushort* __restrict__ qd, const ushort* __restrict__ kd, const ushort* __restrict__ vd,
    const ushort* __restrict__ gth, float* __restrict__ O, float* __restrict__ ss)
{
    __shared__ ushort Ks[64 * 72];
    __shared__ ushort Vs[64 * 72];
    __shared__ ushort Ps[64 * 72];
    __shared__ ushort Ms[64 * 72];   // holds Q during prologue, then mask tiles
    __shared__ float red[4];
    const int s0 = blockIdx.x * 64;
    const int bh = blockIdx.y;
    const int mm = bh & 3;           // h = bh & 15; mm = h & 3 = bh & 3
    const int tid = threadIdx.x, lane = tid & 63, wave = tid >> 6;
    const int l31 = lane & 31, hl = lane >> 5;
    const int wr2 = wave >> 1, wc2 = wave & 1;

    // stage Q tile into Ms, pull A-frags to registers, then Ms is free for mask
    #pragma unroll
    for (int i = 0; i < 2; i++) {
        int c = tid + i * 256;
        int r = c >> 3, off = (c & 7) * 8;
        *(uint4*)&Ms[r * 72 + off] = *(const uint4*)&qd[(bh * 1024 + s0 + r) * 64 + off];
    }
    __syncthreads();
    bf16x8 qf[4];
    #pragma unroll
    for (int kk = 0; kk < 4; kk++)
        qf[kk] = *(const bf16x8*)&Ms[(wr2 * 32 + l31) * 72 + kk * 16 + hl * 8];

    f32x16 oacc;
    #pragma unroll
    for (int i = 0; i < 16; i++) oacc[i] = 0.f;
    float ssacc = 0.f;
    const ushort* gbase = gth + mm * 1048576 + s0 * 1024;

    for (int t0 = 0; t0 < 1024; t0 += 64) {
        __syncthreads();   // prev-iter readers (and prologue qf reads) done before restage
        #pragma unroll
        for (int i = 0; i < 2; i++) {
            int c = tid + i * 256;
            int r = c >> 3, off = (c & 7) * 8;
            *(uint4*)&Ks[r * 72 + off] = *(const uint4*)&kd[(bh * 1024 + t0 + r) * 64 + off];
            *(uint4*)&Vs[r * 72 + off] = *(const uint4*)&vd[(bh * 64 + r) * 1024 + t0 + off];
            *(uint4*)&Ms[r * 72 + off] = *(const uint4*)&gbase[r * 1024 + t0 + off];
        }
        __syncthreads();

        // QK^T: wave computes P tile rows [wr2*32,+32), cols [wc2*32,+32)
        f32x16 p;
        #pragma unroll
        for (int i = 0; i < 16; i++) p[i] = 0.f;
        #pragma unroll
        for (int kk = 0; kk < 4; kk++) {
            bf16x8 b = *(const bf16x8*)&Ks[(wc2 * 32 + l31) * 72 + kk * 16 + hl * 8];
            p = __builtin_amdgcn_mfma_f32_32x32x16_bf16(qf[kk], b, p, 0, 0, 0);
        }
        // multiply by mask (from LDS), accumulate square-sum, write P tile
        {
            const int col = wc2 * 32 + l31;
            #pragma unroll
            for (int reg = 0; reg < 16; reg++) {
                int row = wr2 * 32 + (reg & 3) + 8 * (reg >> 2) + 4 * hl;
                float pv = p[reg] * bf2f(Ms[row * 72 + col]);
                ssacc += pv * pv;
                Ps[row * 72 + col] = f2bf(pv);
            }
        }
        __syncthreads();
        // PV: wave computes O rows [wr2*32,+32), dh cols [wc2*32,+32)
        #pragma unroll
        for (int kk = 0; kk < 4; kk++) {
            bf16x8 a = *(const bf16x8*)&Ps[(wr2 * 32 + l31) * 72 + kk * 16 + hl * 8];
            bf16x8 b = *(const bf16x8*)&Vs[(wc2 * 32 + l31) * 72 + kk * 16 + hl * 8];
            oacc = __builtin_amdgcn_mfma_f32_32x32x16_bf16(a, b, oacc, 0, 0, 0);
        }
    }
    #pragma unroll
    for (int reg = 0; reg < 16; reg++) {
        int s = s0 + wr2 * 32 + (reg & 3) + 8 * (reg >> 2) + 4 * hl;
        int dh = wc2 * 32 + l31;
        O[(bh * 1024 + s) * 64 + dh] = oacc[reg];
    }
    for (int off = 32; off; off >>= 1) ssacc += __shfl_down(ssacc, off, 64);
    if (lane == 0) red[wave] = ssacc;
    __syncthreads();
    if (tid == 0) atomicAdd(&ss[bh], red[0] + red[1] + red[2] + red[3]);
}

// ---------------- normalize + transpose to [B,S,H,DH] ----------------
__global__ __launch_bounds__(256) void normalize_out(const float* __restrict__ O,
                                                     const float* __restrict__ ss,
                                                     float* __restrict__ out)
{
    int gid = blockIdx.x * 256 + threadIdx.x;
    int e = gid * 4;
    int bh = e >> 16;
    float inv = 1.f / (sqrtf(ss[bh]) + 1e-8f);
    float4 v4 = *(const float4*)&O[e];
    int b_ = bh >> 4, h = bh & 15;
    int s = (e >> 6) & 1023, dh = e & 63;
    float4 o4 = {v4.x * inv, v4.y * inv, v4.z * inv, v4.w * inv};
    *(float4*)&out[((b_ * 1024 + s) * 16 + h) * 64 + dh] = o4;
}

extern "C" void kernel_launch(void* const* d_in, const int* in_sizes, int n_in,
                              void* d_out, int out_size, void* d_ws, size_t ws_size,
                              hipStream_t stream) {
    const float* x  = (const float*)d_in[0];
    const float* Wk = (const float*)d_in[1];
    const float* bk = (const float*)d_in[2];
    const float* Wq = (const float*)d_in[3];
    const float* bq = (const float*)d_in[4];
    const float* Wv = (const float*)d_in[5];
    const float* bv = (const float*)d_in[6];
    const float* m1 = (const float*)d_in[7];
    const float* m2 = (const float*)d_in[8];
    const int*   rb = (const int*)d_in[9];
    float* out = (float*)d_out;

    char* ws = (char*)d_ws;
    ushort* xb    = (ushort*)(ws);                  //  8 MB  [4096,1024] bf16
    ushort* wball = (ushort*)(ws + 8388608);        //  6 MB  3x[1024,1024] bf16
    ushort* kd    = (ushort*)(ws + 14680064);       //  8 MB  [B,H,S,DH] bf16
    ushort* qd    = (ushort*)(ws + 23068672);       //  8 MB
    ushort* vd    = (ushort*)(ws + 31457280);       //  8 MB  [B,H,DH,S] bf16
    float*  lm    = (float*)(ws + 39845888);        // 16 MB  [M,S,S] f32 (reused as O)
    ushort* gth   = (ushort*)(ws + 56623104);       //  8 MB  [M,S,S] bf16
    float*  ssb   = (float*)(ws + 65011712);        // 64 f32

    convert_all<<<7168, 256, 0, stream>>>(x, Wk, Wq, Wv, xb, wball);
    proj_gemm<<<dim3(32, 8, 3), 256, 0, stream>>>(xb, wball, bk, bq, bv, kd, qd, vd);
    mask_lr<<<dim3(16, 16, 4), 256, 0, stream>>>(m1, m2, lm);
    mask_gather<<<dim3(1024, 4), 256, 0, stream>>>(lm, rb, gth);
    hipMemsetAsync(ssb, 0, 64 * sizeof(float), stream);
    float* O = lm;   // lm dead after mask_gather
    attention<<<dim3(16, 64), 256, 0, stream>>>(qd, kd, vd, gth, O, ssb);
    normalize_out<<<4096, 256, 0, stream>>>(O, ssb, out);
}

// Round 4
// 204.446 us; speedup vs baseline: 1.4731x; 1.0497x over previous
//
#include <hip/hip_runtime.h>
#include <hip/hip_bf16.h>
#include <stdint.h>

typedef __attribute__((ext_vector_type(8))) __bf16 bf16x8;
typedef __attribute__((ext_vector_type(4))) float  f32x4;
typedef __attribute__((ext_vector_type(16))) float f32x16;

__device__ __forceinline__ ushort f2bf(float f) {
    union { float f; uint32_t u; } v; v.f = f;
    uint32_t u = v.u;
    uint32_t r = 0x7FFFu + ((u >> 16) & 1u);
    return (ushort)((u + r) >> 16);
}
__device__ __forceinline__ float bf2f(ushort u) {
    union { uint32_t u; float f; } v; v.u = ((uint32_t)u) << 16;
    return v.f;
}

// async global->LDS, 16B per lane; LDS dest must be wave-uniform base + lane*16
typedef __attribute__((address_space(3))) uint32_t lds_u32_t;
typedef const __attribute__((address_space(1))) uint32_t glb_u32_t;
__device__ __forceinline__ void async_copy16(const void* g, void* l) {
    __builtin_amdgcn_global_load_lds((glb_u32_t*)g, (lds_u32_t*)l, 16, 0, 0);
}

// ------------- merged convert fp32 -> bf16: x then Wk,Wq,Wv -------------
__global__ __launch_bounds__(256) void convert_all(
    const float* __restrict__ x, const float* __restrict__ wk,
    const float* __restrict__ wq, const float* __restrict__ wv,
    ushort* __restrict__ xb, ushort* __restrict__ wball)
{
    int i = blockIdx.x * 256 + threadIdx.x;   // 1835008 float4 chunks total
    const float* src; ushort* dst; int j;
    if (i < 1048576) { src = x; dst = xb; j = i; }
    else {
        int t = i - 1048576;
        int z = t >> 18;             // 0..2
        j = t & 262143;
        src = (z == 0) ? wk : (z == 1) ? wq : wv;
        dst = wball + z * 1048576;
    }
    float4 f = ((const float4*)src)[j];
    ushort4 o;
    o.x = f2bf(f.x); o.y = f2bf(f.y); o.z = f2bf(f.z); o.w = f2bf(f.w);
    ((ushort4*)dst)[j] = o;
}

// ---------------- QKV projection GEMM: Y = X @ W^T + b ----------------
// BK=64, XOR chunk-swizzled LDS (row r chunk j stored at j^(r&7)) to spread
// ds_read_b128 frag reads across all 8 bank groups. 16 K-iterations.
__global__ __launch_bounds__(256) void proj_gemm(
    const ushort* __restrict__ xb, const ushort* __restrict__ wball,
    const float* __restrict__ bk, const float* __restrict__ bq, const float* __restrict__ bv,
    ushort* __restrict__ kd, ushort* __restrict__ qd, ushort* __restrict__ vd)
{
    __shared__ ushort As[128 * 64];   // 16 KB
    __shared__ ushort Bs[128 * 64];   // 16 KB
    const int z = blockIdx.z;
    const int row0 = blockIdx.x * 128;
    const int col0 = blockIdx.y * 128;
    const ushort* wb = wball + z * 1048576;
    const int tid = threadIdx.x;
    const int lane = tid & 63, wave = tid >> 6;
    const int quad = lane >> 4, m15 = lane & 15;
    const int wr = wave >> 1, wc = wave & 1;

    f32x4 acc[4][4];
    for (int i = 0; i < 4; i++)
        for (int j = 0; j < 4; j++) acc[i][j] = (f32x4){0.f, 0.f, 0.f, 0.f};

    // per-thread staged chunks: c = tid + i*256, i=0..3 (1024 chunks of 16B per array)
    // row r = c>>3, stored pos cjp = c&7, logical chunk cj = cjp ^ (r&7)
    for (int kk = 0; kk < 1024; kk += 64) {
        __syncthreads();
        #pragma unroll
        for (int i = 0; i < 4; i++) {
            int c = tid + i * 256;
            int r = c >> 3, cjp = c & 7;
            int cj = cjp ^ (r & 7);
            async_copy16(&xb[(row0 + r) * 1024 + kk + cj * 8], &As[c * 8]);
            async_copy16(&wb[(col0 + r) * 1024 + kk + cj * 8], &Bs[c * 8]);
        }
        __syncthreads();
        #pragma unroll
        for (int kh = 0; kh < 2; kh++) {          // two K=32 halves of the BK=64 tile
            bf16x8 af[4], bfv[4];
            #pragma unroll
            for (int fr = 0; fr < 4; fr++) {
                int row = wr * 64 + fr * 16 + m15;
                int q4 = kh * 4 + quad;
                af[fr] = *(const bf16x8*)&As[row * 64 + ((q4 ^ (row & 7)) * 8)];
            }
            #pragma unroll
            for (int fc = 0; fc < 4; fc++) {
                int row = wc * 64 + fc * 16 + m15;
                int q4 = kh * 4 + quad;
                bfv[fc] = *(const bf16x8*)&Bs[row * 64 + ((q4 ^ (row & 7)) * 8)];
            }
            #pragma unroll
            for (int fr = 0; fr < 4; fr++)
                #pragma unroll
                for (int fc = 0; fc < 4; fc++)
                    acc[fr][fc] = __builtin_amdgcn_mfma_f32_16x16x32_bf16(af[fr], bfv[fc], acc[fr][fc], 0, 0, 0);
        }
    }

    const float* bias = (z == 0) ? bk : (z == 1) ? bq : bv;
    ushort* dstA = (z == 0) ? kd : qd;
    for (int fr = 0; fr < 4; fr++) {
        int ibase = row0 + wr * 64 + fr * 16 + quad * 4;
        int b_ = ibase >> 10, s = ibase & 1023;
        for (int fc = 0; fc < 4; fc++) {
            int j = col0 + wc * 64 + fc * 16 + m15;
            int h = j >> 6, dh = j & 63;
            float bb = bias[j];
            if (z < 2) {
                for (int r = 0; r < 4; r++)
                    dstA[((b_ * 16 + h) * 1024 + (s + r)) * 64 + dh] = f2bf(acc[fr][fc][r] + bb);
            } else {
                ushort4 o;
                o.x = f2bf(acc[fr][fc][0] + bb);
                o.y = f2bf(acc[fr][fc][1] + bb);
                o.z = f2bf(acc[fr][fc][2] + bb);
                o.w = f2bf(acc[fr][fc][3] + bb);
                *(ushort4*)&vd[((b_ * 16 + h) * 64 + dh) * 1024 + s] = o;
            }
        }
    }
}

// ------- fused mask: lm rows (8 per block) in LDS, then gather -> bf16 -------
// lm[m,s,u] = sum_r m1[m,r,s]*m2[m,r,u];  gth[m,s,t] = bf16(lm[m,s,rb[m,s,t]]*0.125)
__global__ __launch_bounds__(256) void mask_fused(
    const float* __restrict__ m1, const float* __restrict__ m2,
    const int* __restrict__ rb, ushort* __restrict__ gth)
{
    __shared__ float As8[64 * 8];     // m1[m][r][s0..s0+7]    2 KB
    __shared__ float lmS[8 * 1024];   // lm rows               32 KB
    const int s0 = blockIdx.x * 8;
    const int m = blockIdx.y;
    const int tid = threadIdx.x;

    if (tid < 128) {
        int r = tid >> 1, half = tid & 1;
        *(float4*)&As8[r * 8 + half * 4] =
            *(const float4*)&m1[(m * 64 + r) * 1024 + s0 + half * 4];
    }
    __syncthreads();

    // each thread owns u-columns [tid*4, tid*4+4) for all 8 s rows
    f32x4 acc8[8];
    #pragma unroll
    for (int s = 0; s < 8; s++) acc8[s] = (f32x4){0.f, 0.f, 0.f, 0.f};
    const float* m2b = m2 + m * 65536 + tid * 4;
    #pragma unroll 4
    for (int r = 0; r < 64; r++) {
        float4 b4 = *(const float4*)&m2b[r * 1024];
        f32x4 b = (f32x4){b4.x, b4.y, b4.z, b4.w};
        #pragma unroll
        for (int s = 0; s < 8; s++) {
            float a = As8[r * 8 + s];
            acc8[s] += a * b;
        }
    }
    #pragma unroll
    for (int s = 0; s < 8; s++)
        *(f32x4*)&lmS[s * 1024 + tid * 4] = acc8[s];
    __syncthreads();

    // gather: 8 rows x 1024, int4-coalesced reads of rb
    const int base = (m * 1024 + s0) * 1024;
    #pragma unroll
    for (int i = 0; i < 8; i++) {
        int c = tid + i * 256;             // 2048 int4 chunks
        int row = c >> 8, j = (c & 255) * 4;
        int4 idx = *(const int4*)&rb[base + row * 1024 + j];
        ushort4 o;
        o.x = f2bf(lmS[row * 1024 + (idx.x & 1023)] * 0.125f);
        o.y = f2bf(lmS[row * 1024 + (idx.y & 1023)] * 0.125f);
        o.z = f2bf(lmS[row * 1024 + (idx.z & 1023)] * 0.125f);
        o.w = f2bf(lmS[row * 1024 + (idx.w & 1023)] * 0.125f);
        *(ushort4*)&gth[base + row * 1024 + j] = o;
    }
}

// ---------------- fused attention: O_unnorm = (QK^T*mask) @ V ; ss = sum P^2 ----------------
// q,k: [B,H,S,64] bf16 ; v: [B,H,64,S] bf16 ; gth: [4,S,S] bf16 (scale folded in)
__global__ __launch_bounds__(256, 2) void attention(
    const ushort* __restrict__ qd, const ushort* __restrict__ kd, const ushort* __restrict__ vd,
    const ushort* __restrict__ gth, float* __restrict__ O, float* __restrict__ ss)
{
    __shared__ ushort Ks[64 * 72];
    __shared__ ushort Vs[64 * 72];
    __shared__ ushort Ps[64 * 72];
    __shared__ ushort Ms[64 * 72];   // holds Q during prologue, then mask tiles
    __shared__ float red[4];
    const int s0 = blockIdx.x * 64;
    const int bh = blockIdx.y;
    const int mm = bh & 3;           // h = bh & 15; mm = h & 3 = bh & 3
    const int tid = threadIdx.x, lane = tid & 63, wave = tid >> 6;
    const int l31 = lane & 31, hl = lane >> 5;
    const int wr2 = wave >> 1, wc2 = wave & 1;

    // stage Q tile into Ms, pull A-frags to registers, then Ms is free for mask
    #pragma unroll
    for (int i = 0; i < 2; i++) {
        int c = tid + i * 256;
        int r = c >> 3, off = (c & 7) * 8;
        *(uint4*)&Ms[r * 72 + off] = *(const uint4*)&qd[(bh * 1024 + s0 + r) * 64 + off];
    }
    __syncthreads();
    bf16x8 qf[4];
    #pragma unroll
    for (int kk = 0; kk < 4; kk++)
        qf[kk] = *(const bf16x8*)&Ms[(wr2 * 32 + l31) * 72 + kk * 16 + hl * 8];

    f32x16 oacc;
    #pragma unroll
    for (int i = 0; i < 16; i++) oacc[i] = 0.f;
    float ssacc = 0.f;
    const ushort* gbase = gth + mm * 1048576 + s0 * 1024;

    for (int t0 = 0; t0 < 1024; t0 += 64) {
        __syncthreads();   // prev-iter readers (and prologue qf reads) done before restage
        #pragma unroll
        for (int i = 0; i < 2; i++) {
            int c = tid + i * 256;
            int r = c >> 3, off = (c & 7) * 8;
            *(uint4*)&Ks[r * 72 + off] = *(const uint4*)&kd[(bh * 1024 + t0 + r) * 64 + off];
            *(uint4*)&Vs[r * 72 + off] = *(const uint4*)&vd[(bh * 64 + r) * 1024 + t0 + off];
            *(uint4*)&Ms[r * 72 + off] = *(const uint4*)&gbase[r * 1024 + t0 + off];
        }
        __syncthreads();

        // QK^T: wave computes P tile rows [wr2*32,+32), cols [wc2*32,+32)
        f32x16 p;
        #pragma unroll
        for (int i = 0; i < 16; i++) p[i] = 0.f;
        #pragma unroll
        for (int kk = 0; kk < 4; kk++) {
            bf16x8 b = *(const bf16x8*)&Ks[(wc2 * 32 + l31) * 72 + kk * 16 + hl * 8];
            p = __builtin_amdgcn_mfma_f32_32x32x16_bf16(qf[kk], b, p, 0, 0, 0);
        }
        // multiply by mask (from LDS), accumulate square-sum, write P tile
        {
            const int col = wc2 * 32 + l31;
            #pragma unroll
            for (int reg = 0; reg < 16; reg++) {
                int row = wr2 * 32 + (reg & 3) + 8 * (reg >> 2) + 4 * hl;
                float pv = p[reg] * bf2f(Ms[row * 72 + col]);
                ssacc += pv * pv;
                Ps[row * 72 + col] = f2bf(pv);
            }
        }
        __syncthreads();
        // PV: wave computes O rows [wr2*32,+32), dh cols [wc2*32,+32)
        #pragma unroll
        for (int kk = 0; kk < 4; kk++) {
            bf16x8 a = *(const bf16x8*)&Ps[(wr2 * 32 + l31) * 72 + kk * 16 + hl * 8];
            bf16x8 b = *(const bf16x8*)&Vs[(wc2 * 32 + l31) * 72 + kk * 16 + hl * 8];
            oacc = __builtin_amdgcn_mfma_f32_32x32x16_bf16(a, b, oacc, 0, 0, 0);
        }
    }
    #pragma unroll
    for (int reg = 0; reg < 16; reg++) {
        int s = s0 + wr2 * 32 + (reg & 3) + 8 * (reg >> 2) + 4 * hl;
        int dh = wc2 * 32 + l31;
        O[(bh * 1024 + s) * 64 + dh] = oacc[reg];
    }
    for (int off = 32; off; off >>= 1) ssacc += __shfl_down(ssacc, off, 64);
    if (lane == 0) red[wave] = ssacc;
    __syncthreads();
    if (tid == 0) atomicAdd(&ss[bh], red[0] + red[1] + red[2] + red[3]);
}

// ---------------- normalize + transpose to [B,S,H,DH] ----------------
__global__ __launch_bounds__(256) void normalize_out(const float* __restrict__ O,
                                                     const float* __restrict__ ss,
                                                     float* __restrict__ out)
{
    int gid = blockIdx.x * 256 + threadIdx.x;
    int e = gid * 4;
    int bh = e >> 16;
    float inv = 1.f / (sqrtf(ss[bh]) + 1e-8f);
    float4 v4 = *(const float4*)&O[e];
    int b_ = bh >> 4, h = bh & 15;
    int s = (e >> 6) & 1023, dh = e & 63;
    float4 o4 = {v4.x * inv, v4.y * inv, v4.z * inv, v4.w * inv};
    *(float4*)&out[((b_ * 1024 + s) * 16 + h) * 64 + dh] = o4;
}

extern "C" void kernel_launch(void* const* d_in, const int* in_sizes, int n_in,
                              void* d_out, int out_size, void* d_ws, size_t ws_size,
                              hipStream_t stream) {
    const float* x  = (const float*)d_in[0];
    const float* Wk = (const float*)d_in[1];
    const float* bk = (const float*)d_in[2];
    const float* Wq = (const float*)d_in[3];
    const float* bq = (const float*)d_in[4];
    const float* Wv = (const float*)d_in[5];
    const float* bv = (const float*)d_in[6];
    const float* m1 = (const float*)d_in[7];
    const float* m2 = (const float*)d_in[8];
    const int*   rb = (const int*)d_in[9];
    float* out = (float*)d_out;

    char* ws = (char*)d_ws;
    ushort* xb    = (ushort*)(ws);                  //  8 MB  [4096,1024] bf16
    ushort* wball = (ushort*)(ws + 8388608);        //  6 MB  3x[1024,1024] bf16
    ushort* kd    = (ushort*)(ws + 14680064);       //  8 MB  [B,H,S,DH] bf16
    ushort* qd    = (ushort*)(ws + 23068672);       //  8 MB
    ushort* vd    = (ushort*)(ws + 31457280);       //  8 MB  [B,H,DH,S] bf16
    float*  O     = (float*)(ws + 39845888);        // 16 MB  [B,H,S,DH] f32
    ushort* gth   = (ushort*)(ws + 56623104);       //  8 MB  [M,S,S] bf16
    float*  ssb   = (float*)(ws + 65011712);        // 64 f32

    convert_all<<<7168, 256, 0, stream>>>(x, Wk, Wq, Wv, xb, wball);
    proj_gemm<<<dim3(32, 8, 3), 256, 0, stream>>>(xb, wball, bk, bq, bv, kd, qd, vd);
    mask_fused<<<dim3(128, 4), 256, 0, stream>>>(m1, m2, rb, gth);
    hipMemsetAsync(ssb, 0, 64 * sizeof(float), stream);
    attention<<<dim3(16, 64), 256, 0, stream>>>(qd, kd, vd, gth, O, ssb);
    normalize_out<<<4096, 256, 0, stream>>>(O, ssb, out);
}